// Round 20
// baseline (136.675 us; speedup 1.0000x reference)
//
#include <hip/hip_runtime.h>
#include <hip/hip_fp16.h>

#define IN_DIM 128
#define HID    32
#define CHUNK  6144      // edges per sort block (12/thread)
#define EPT    12        // edges per thread in sort half
#define BSH    9         // log2(nodes per bucket)
#define BSIZE  512       // nodes per bucket
#define CAPSH  14        // per-bucket slot capacity = 16384 (mean 12245 + 37 sigma)
#define ROWBITS 17       // N = 100000 < 2^17
#define STRIDE 5         // sort blocks interleaved every STRIDE grid slots

typedef union { float2 f2; __half2 h2[2]; } hpack;

// cursor[b] = b * CAP
__global__ void k_init_cursor(int* __restrict__ cursor) {
    cursor[threadIdx.x] = threadIdx.x << CAPSH;
}

// ======================= fused: bucket-sort + x@W1, interleaved block mapping =======================
// (exact round-17 form: fusedA 39.8 us @ VGPR 32, occupancy ~58%)

__global__ __launch_bounds__(512) void k_fusedA(const int* __restrict__ row,
                                                const int* __restrict__ col,
                                                int* __restrict__ cursor,
                                                int* __restrict__ bpack,
                                                const float* __restrict__ x,
                                                const float* __restrict__ W1,
                                                float* __restrict__ T0,
                                                int E, int N, int gBuild) {
    __shared__ __align__(16) char smem[34816];
    int tid = threadIdx.x;

    int b = blockIdx.x;
    int q = b / STRIDE, r = b % STRIDE;
    bool isSort = (r == 0) && (q < gBuild);

    if (isSort) {
        int* lh   = (int*)smem;            // 256 counts (preserved)
        int* ls   = lh + 256;              // exclusive local starts
        int* gdst = ls + 256;              // global dst - local start
        int* sp   = gdst + 256;            // CHUNK packed edges
        unsigned char* sb = (unsigned char*)(sp + CHUNK); // CHUNK bucket ids

        if (tid < 256) lh[tid] = 0;
        __syncthreads();

        int base = q * CHUNK;
        int nE = min(CHUNK, E - base);
        int e0 = tid * EPT;
        int m  = min(EPT, nE - e0);

        int ecol[EPT], erow[EPT], rk[EPT];
        if (m == EPT) {
            int4 ca = *(const int4*)(col + base + e0);
            int4 cb = *(const int4*)(col + base + e0 + 4);
            int4 cc = *(const int4*)(col + base + e0 + 8);
            int4 ra = *(const int4*)(row + base + e0);
            int4 rb = *(const int4*)(row + base + e0 + 4);
            int4 rc = *(const int4*)(row + base + e0 + 8);
            ecol[0]=ca.x; ecol[1]=ca.y; ecol[2]=ca.z;  ecol[3]=ca.w;
            ecol[4]=cb.x; ecol[5]=cb.y; ecol[6]=cb.z;  ecol[7]=cb.w;
            ecol[8]=cc.x; ecol[9]=cc.y; ecol[10]=cc.z; ecol[11]=cc.w;
            erow[0]=ra.x; erow[1]=ra.y; erow[2]=ra.z;  erow[3]=ra.w;
            erow[4]=rb.x; erow[5]=rb.y; erow[6]=rb.z;  erow[7]=rb.w;
            erow[8]=rc.x; erow[9]=rc.y; erow[10]=rc.z; erow[11]=rc.w;
        } else {
            for (int j = 0; j < m; ++j) {
                ecol[j] = col[base + e0 + j];
                erow[j] = row[base + e0 + j];
            }
        }

        for (int j = 0; j < m; ++j)
            rk[j] = atomicAdd(&lh[ecol[j] >> BSH], 1);
        __syncthreads();

        int v = 0;
        if (tid < 256) { v = lh[tid]; ls[tid] = v; }
        __syncthreads();
        for (int off = 1; off < 256; off <<= 1) {
            int nv = 0;
            if (tid < 256) nv = ls[tid] + (tid >= off ? ls[tid - off] : 0);
            __syncthreads();
            if (tid < 256) ls[tid] = nv;
            __syncthreads();
        }
        if (tid < 256) ls[tid] -= v;
        __syncthreads();

        if (tid < 256) {
            int bb = (tid + q) & 255;
            int vb = lh[bb];
            if (vb) gdst[bb] = atomicAdd(&cursor[bb], vb) - ls[bb];
        }
        __syncthreads();

        for (int j = 0; j < m; ++j) {
            int c = ecol[j];
            int bk = c >> BSH;
            int idx = ls[bk] + rk[j];
            sp[idx] = ((c & (BSIZE - 1)) << ROWBITS) | erow[j];
            sb[idx] = (unsigned char)bk;
        }
        __syncthreads();

        for (int i = tid; i < nE; i += 512) {
            int bk = sb[i];
            bpack[gdst[bk] + i] = sp[i];
        }
    } else {
        // ---- t1 = x @ W1 (unscaled), fp16 out; float4 x loads ----
        int xIdx = b - min(q + (r > 0 ? 1 : 0), gBuild);   // compact xform index

        float* lw = (float*)smem;          // 16 KB
        for (int i = tid; i < IN_DIM * HID; i += 512) lw[i] = W1[i];
        __syncthreads();

        int lane = tid & 7;
        int jb = lane * 4;
        int n  = xIdx * 64 + (tid >> 3);
        if (n >= N) return;

        const float4* xr4 = (const float4*)(x + (size_t)n * IN_DIM);
        float a0 = 0.f, a1 = 0.f, a2 = 0.f, a3 = 0.f;
        #pragma unroll 8
        for (int kq = 0; kq < IN_DIM / 4; ++kq) {
            float4 v = xr4[kq];
            const float* w0 = &lw[(kq * 4 + 0) * HID + jb];
            const float* w1 = &lw[(kq * 4 + 1) * HID + jb];
            const float* w2 = &lw[(kq * 4 + 2) * HID + jb];
            const float* w3 = &lw[(kq * 4 + 3) * HID + jb];
            a0 = fmaf(v.x, w0[0], a0); a1 = fmaf(v.x, w0[1], a1);
            a2 = fmaf(v.x, w0[2], a2); a3 = fmaf(v.x, w0[3], a3);
            a0 = fmaf(v.y, w1[0], a0); a1 = fmaf(v.y, w1[1], a1);
            a2 = fmaf(v.y, w1[2], a2); a3 = fmaf(v.y, w1[3], a3);
            a0 = fmaf(v.z, w2[0], a0); a1 = fmaf(v.z, w2[1], a1);
            a2 = fmaf(v.z, w2[2], a2); a3 = fmaf(v.z, w2[3], a3);
            a0 = fmaf(v.w, w3[0], a0); a1 = fmaf(v.w, w3[1], a1);
            a2 = fmaf(v.w, w3[2], a2); a3 = fmaf(v.w, w3[3], a3);
        }
        hpack u;
        u.h2[0] = __floats2half2_rn(a0, a1);
        u.h2[1] = __floats2half2_rn(a2, a3);
        ((float2*)T0)[(size_t)n * 8 + lane] = u.f2;
    }
}

// ======================= kC: per-bucket CSR fill + deg/dinv + B0 scale =======================

__global__ __launch_bounds__(1024) void kC_fill(const int* __restrict__ bpack,
                                                const int* __restrict__ cursor,
                                                int* __restrict__ csr,
                                                int* __restrict__ rowptr,
                                                int* __restrict__ deg,
                                                float* __restrict__ dinv,
                                                float* __restrict__ B0, int N) {
    __shared__ int cnt[BSIZE], ex[BSIZE], c2[BSIZE];
    __shared__ int sp[1 << CAPSH];     // 64 KB staged bucket edges
    int tid = threadIdx.x;
    int b = blockIdx.x;
    int s = b << CAPSH;
    int ne = cursor[b] - s;
    int c0 = b << BSH;

    if (tid < BSIZE) { cnt[tid] = 0; c2[tid] = 0; }
    __syncthreads();

    for (int i = tid; i < ne; i += 1024) {
        int v = bpack[s + i];
        sp[i] = v;
        atomicAdd(&cnt[v >> ROWBITS], 1);
    }
    __syncthreads();

    if (tid < BSIZE) ex[tid] = cnt[tid];
    __syncthreads();
    for (int off = 1; off < BSIZE; off <<= 1) {
        int nv = 0;
        if (tid < BSIZE) nv = ex[tid] + (tid >= off ? ex[tid - off] : 0);
        __syncthreads();
        if (tid < BSIZE) ex[tid] = nv;
        __syncthreads();
    }

    if (tid < BSIZE) {
        int ev = ex[tid] - cnt[tid];
        ex[tid] = ev;
        int n = c0 + tid;
        if (n < N) {
            rowptr[n] = s + ev;
            deg[n]    = cnt[tid];
            dinv[n]   = rsqrtf((float)cnt[tid] + 1.0f);
        }
    }
    __syncthreads();

    for (int i = tid; i < ne; i += 1024) {
        int v = sp[i];
        int c = v >> ROWBITS;
        int k = atomicAdd(&c2[c], 1);
        csr[s + ex[c] + k] = v & ((1 << ROWBITS) - 1);
    }

    for (int j = tid; j < BSIZE * 4; j += 1024) {
        int nl = j >> 2;
        int n = c0 + nl;
        if (n < N) {
            float dv = rsqrtf((float)cnt[nl] + 1.0f);
            union { float4 f4; __half2 h2[4]; } u;
            u.f4 = ((const float4*)B0)[(size_t)n * 4 + (j & 3)];
            #pragma unroll
            for (int qq = 0; qq < 4; ++qq) {
                float2 f = __half22float2(u.h2[qq]);
                u.h2[qq] = __floats2half2_rn(f.x * dv, f.y * dv);
            }
            ((float4*)B0)[(size_t)n * 4 + (j & 3)] = u.f4;
        }
    }
}

// ======================= fused gather + transform kernels (16-deep gather ILP) =======================

#define GLOAD(i, r) hpack p##i; p##i.f2 = B2[(size_t)(r) * 8 + lane]
#define GACC(i) { float2 a = __half22float2(p##i.h2[0]), b = __half22float2(p##i.h2[1]); \
                  acc.x += a.x; acc.y += a.y; acc.z += b.x; acc.w += b.y; }

// gather(B0) -> h1 = relu(...) -> s2 = dinv * (h1 @ W2), fp16 out. H never stored.
__global__ __launch_bounds__(256) void k_gxf2(const int* __restrict__ rowptr,
                                              const int* __restrict__ deg,
                                              const int* __restrict__ csr,
                                              const float* __restrict__ Bin,
                                              const float* __restrict__ dinv,
                                              const float* __restrict__ bias,
                                              const float* __restrict__ W2,
                                              float* __restrict__ Bout, int N) {
    __shared__ float lw[HID * HID];
    for (int i = threadIdx.x; i < HID * HID; i += 256) lw[i] = W2[i];
    __syncthreads();

    int lane = threadIdx.x & 7;
    int jb = lane * 4;
    int n  = blockIdx.x * 32 + (threadIdx.x >> 3);
    if (n >= N) return;

    const float2* B2 = (const float2*)Bin;
    hpack u0; u0.f2 = B2[(size_t)n * 8 + lane];     // self-loop term
    float2 l0 = __half22float2(u0.h2[0]);
    float2 l1 = __half22float2(u0.h2[1]);
    float4 acc = make_float4(l0.x, l0.y, l1.x, l1.y);

    int s = rowptr[n], cnt = deg[n];
    int k = 0;
    for (; k + 15 < cnt; k += 16) {
        int r0 = csr[s+k],    r1 = csr[s+k+1],  r2 = csr[s+k+2],  r3 = csr[s+k+3];
        int r4 = csr[s+k+4],  r5 = csr[s+k+5],  r6 = csr[s+k+6],  r7 = csr[s+k+7];
        int r8 = csr[s+k+8],  r9 = csr[s+k+9],  rA = csr[s+k+10], rB = csr[s+k+11];
        int rC = csr[s+k+12], rD = csr[s+k+13], rE = csr[s+k+14], rF = csr[s+k+15];
        GLOAD(0, r0); GLOAD(1, r1); GLOAD(2, r2); GLOAD(3, r3);
        GLOAD(4, r4); GLOAD(5, r5); GLOAD(6, r6); GLOAD(7, r7);
        GLOAD(8, r8); GLOAD(9, r9); GLOAD(10, rA); GLOAD(11, rB);
        GLOAD(12, rC); GLOAD(13, rD); GLOAD(14, rE); GLOAD(15, rF);
        GACC(0); GACC(1); GACC(2); GACC(3); GACC(4); GACC(5); GACC(6); GACC(7);
        GACC(8); GACC(9); GACC(10); GACC(11); GACC(12); GACC(13); GACC(14); GACC(15);
    }
    for (; k + 7 < cnt; k += 8) {
        int r0 = csr[s+k],   r1 = csr[s+k+1], r2 = csr[s+k+2], r3 = csr[s+k+3];
        int r4 = csr[s+k+4], r5 = csr[s+k+5], r6 = csr[s+k+6], r7 = csr[s+k+7];
        GLOAD(0, r0); GLOAD(1, r1); GLOAD(2, r2); GLOAD(3, r3);
        GLOAD(4, r4); GLOAD(5, r5); GLOAD(6, r6); GLOAD(7, r7);
        GACC(0); GACC(1); GACC(2); GACC(3); GACC(4); GACC(5); GACC(6); GACC(7);
    }
    for (; k + 3 < cnt; k += 4) {
        int r0 = csr[s+k], r1 = csr[s+k+1], r2 = csr[s+k+2], r3 = csr[s+k+3];
        GLOAD(0, r0); GLOAD(1, r1); GLOAD(2, r2); GLOAD(3, r3);
        GACC(0); GACC(1); GACC(2); GACC(3);
    }
    for (; k < cnt; ++k) {
        GLOAD(0, csr[s+k]); GACC(0);
    }
    float dv = dinv[n];
    float4 b4 = ((const float4*)bias)[lane];
    float4 o;
    o.x = fmaxf(fmaf(dv, acc.x, b4.x), 0.f);
    o.y = fmaxf(fmaf(dv, acc.y, b4.y), 0.f);
    o.z = fmaxf(fmaf(dv, acc.z, b4.z), 0.f);
    o.w = fmaxf(fmaf(dv, acc.w, b4.w), 0.f);

    // fused h1 @ W2 across the 8-lane group
    float t0 = 0.f, t1 = 0.f, t2 = 0.f, t3 = 0.f;
    #pragma unroll
    for (int sl = 0; sl < 8; ++sl) {
        float h0 = __shfl(o.x, sl, 8);
        float h1 = __shfl(o.y, sl, 8);
        float h2 = __shfl(o.z, sl, 8);
        float h3 = __shfl(o.w, sl, 8);
        const float* w0 = &lw[(sl * 4 + 0) * HID + jb];
        const float* w1 = &lw[(sl * 4 + 1) * HID + jb];
        const float* w2 = &lw[(sl * 4 + 2) * HID + jb];
        const float* w3 = &lw[(sl * 4 + 3) * HID + jb];
        t0 = fmaf(h0, w0[0], t0); t1 = fmaf(h0, w0[1], t1);
        t2 = fmaf(h0, w0[2], t2); t3 = fmaf(h0, w0[3], t3);
        t0 = fmaf(h1, w1[0], t0); t1 = fmaf(h1, w1[1], t1);
        t2 = fmaf(h1, w1[2], t2); t3 = fmaf(h1, w1[3], t3);
        t0 = fmaf(h2, w2[0], t0); t1 = fmaf(h2, w2[1], t1);
        t2 = fmaf(h2, w2[2], t2); t3 = fmaf(h2, w2[3], t3);
        t0 = fmaf(h3, w3[0], t0); t1 = fmaf(h3, w3[1], t1);
        t2 = fmaf(h3, w3[2], t2); t3 = fmaf(h3, w3[3], t3);
    }
    hpack w;
    w.h2[0] = __floats2half2_rn(t0 * dv, t1 * dv);
    w.h2[1] = __floats2half2_rn(t2 * dv, t3 * dv);
    ((float2*)Bout)[(size_t)n * 8 + lane] = w.f2;
}

// gather(B1) -> h2 = relu(...) -> s3 = dinv * (h2 . W3), f32 scalar out.
__global__ __launch_bounds__(256) void k_gxf3(const int* __restrict__ rowptr,
                                              const int* __restrict__ deg,
                                              const int* __restrict__ csr,
                                              const float* __restrict__ Bin,
                                              const float* __restrict__ dinv,
                                              const float* __restrict__ bias,
                                              const float* __restrict__ W3,
                                              float* __restrict__ s3, int N) {
    __shared__ float lw[HID];
    if (threadIdx.x < HID) lw[threadIdx.x] = W3[threadIdx.x];
    __syncthreads();

    int lane = threadIdx.x & 7;
    int jb = lane * 4;
    int n  = blockIdx.x * 32 + (threadIdx.x >> 3);
    if (n >= N) return;

    const float2* B2 = (const float2*)Bin;
    hpack u0; u0.f2 = B2[(size_t)n * 8 + lane];
    float2 l0 = __half22float2(u0.h2[0]);
    float2 l1 = __half22float2(u0.h2[1]);
    float4 acc = make_float4(l0.x, l0.y, l1.x, l1.y);

    int s = rowptr[n], cnt = deg[n];
    int k = 0;
    for (; k + 15 < cnt; k += 16) {
        int r0 = csr[s+k],    r1 = csr[s+k+1],  r2 = csr[s+k+2],  r3 = csr[s+k+3];
        int r4 = csr[s+k+4],  r5 = csr[s+k+5],  r6 = csr[s+k+6],  r7 = csr[s+k+7];
        int r8 = csr[s+k+8],  r9 = csr[s+k+9],  rA = csr[s+k+10], rB = csr[s+k+11];
        int rC = csr[s+k+12], rD = csr[s+k+13], rE = csr[s+k+14], rF = csr[s+k+15];
        GLOAD(0, r0); GLOAD(1, r1); GLOAD(2, r2); GLOAD(3, r3);
        GLOAD(4, r4); GLOAD(5, r5); GLOAD(6, r6); GLOAD(7, r7);
        GLOAD(8, r8); GLOAD(9, r9); GLOAD(10, rA); GLOAD(11, rB);
        GLOAD(12, rC); GLOAD(13, rD); GLOAD(14, rE); GLOAD(15, rF);
        GACC(0); GACC(1); GACC(2); GACC(3); GACC(4); GACC(5); GACC(6); GACC(7);
        GACC(8); GACC(9); GACC(10); GACC(11); GACC(12); GACC(13); GACC(14); GACC(15);
    }
    for (; k + 7 < cnt; k += 8) {
        int r0 = csr[s+k],   r1 = csr[s+k+1], r2 = csr[s+k+2], r3 = csr[s+k+3];
        int r4 = csr[s+k+4], r5 = csr[s+k+5], r6 = csr[s+k+6], r7 = csr[s+k+7];
        GLOAD(0, r0); GLOAD(1, r1); GLOAD(2, r2); GLOAD(3, r3);
        GLOAD(4, r4); GLOAD(5, r5); GLOAD(6, r6); GLOAD(7, r7);
        GACC(0); GACC(1); GACC(2); GACC(3); GACC(4); GACC(5); GACC(6); GACC(7);
    }
    for (; k + 3 < cnt; k += 4) {
        int r0 = csr[s+k], r1 = csr[s+k+1], r2 = csr[s+k+2], r3 = csr[s+k+3];
        GLOAD(0, r0); GLOAD(1, r1); GLOAD(2, r2); GLOAD(3, r3);
        GACC(0); GACC(1); GACC(2); GACC(3);
    }
    for (; k < cnt; ++k) {
        GLOAD(0, csr[s+k]); GACC(0);
    }
    float dv = dinv[n];
    float4 b4 = ((const float4*)bias)[lane];
    float4 o;
    o.x = fmaxf(fmaf(dv, acc.x, b4.x), 0.f);
    o.y = fmaxf(fmaf(dv, acc.y, b4.y), 0.f);
    o.z = fmaxf(fmaf(dv, acc.z, b4.z), 0.f);
    o.w = fmaxf(fmaf(dv, acc.w, b4.w), 0.f);

    float p = o.x * lw[jb] + o.y * lw[jb + 1] + o.z * lw[jb + 2] + o.w * lw[jb + 3];
    p += __shfl_xor(p, 1, 8);
    p += __shfl_xor(p, 2, 8);
    p += __shfl_xor(p, 4, 8);
    if (lane == 0) s3[n] = p * dv;
}

// out[n] = dinv[n] * (s3[n] + sum_nbrs s3[r]) + b3 ; 8 lanes/node strided.
__global__ __launch_bounds__(256) void k_gather1(const int* __restrict__ rowptr,
                                                 const int* __restrict__ deg,
                                                 const int* __restrict__ csr,
                                                 const float* __restrict__ s3,
                                                 const float* __restrict__ dinv,
                                                 const float* __restrict__ b3,
                                                 float* __restrict__ out, int N) {
    int lane = threadIdx.x & 7;
    int n    = blockIdx.x * 32 + (threadIdx.x >> 3);
    if (n >= N) return;

    int s = rowptr[n], cnt = deg[n];
    float acc = 0.f;
    for (int k = lane; k < cnt; k += 8) acc += s3[csr[s + k]];
    acc += __shfl_xor(acc, 1, 8);
    acc += __shfl_xor(acc, 2, 8);
    acc += __shfl_xor(acc, 4, 8);
    if (lane == 0) out[n] = fmaf(dinv[n], acc + s3[n], b3[0]);
}

// ======================= host launch =======================

static inline size_t align64(size_t x) { return (x + 63) & ~(size_t)63; }

extern "C" void kernel_launch(void* const* d_in, const int* in_sizes, int n_in,
                              void* d_out, int out_size, void* d_ws, size_t ws_size,
                              hipStream_t stream) {
    const float* x   = (const float*)d_in[0];
    const int*   ei  = (const int*)d_in[1];   // jax x64 disabled -> int32
    const float* W1  = (const float*)d_in[2];
    const float* b1  = (const float*)d_in[3];
    const float* W2  = (const float*)d_in[4];
    const float* b2  = (const float*)d_in[5];
    const float* W3  = (const float*)d_in[6];
    const float* b3  = (const float*)d_in[7];

    const int N = in_sizes[0] / IN_DIM;       // 100000
    const int E = in_sizes[1] / 2;            // 2400000
    const int* row = ei;                       // message source
    const int* col = ei + E;                   // aggregation target

    const int NB = (N + BSIZE - 1) / BSIZE;    // 196 buckets
    const size_t bktCap = (size_t)NB << CAPSH; // padded slot count

    // workspace layout (64B-aligned regions)
    char* p = (char*)d_ws;
    size_t off = 0;
    float* dinv   = (float*)(p + off); off = align64(off + (size_t)N * 4);
    float* B0     = (float*)(p + off); off = align64(off + (size_t)N * HID * 2);  // fp16 msgs
    float* B1     = (float*)(p + off); off = align64(off + (size_t)N * HID * 2);  // fp16 msgs
    float* s3     = (float*)(p + off); off = align64(off + (size_t)N * 4);
    int*   deg    = (int*)  (p + off); off = align64(off + (size_t)N * 4);
    int*   rowptr = (int*)  (p + off); off = align64(off + (size_t)N * 4);
    int*   cursor = (int*)  (p + off); off = align64(off + 256 * 4);
    int*   bpack  = (int*)  (p + off); off = align64(off + bktCap * 4);
    int*   csr    = (int*)  (p + off); off = align64(off + bktCap * 4);
    float* out    = (float*)d_out;

    const int gBuild = (E + CHUNK - 1) / CHUNK;   // 391
    const int gX64   = (N + 63) / 64;             // 1563 (xform part, 64 nodes/block)
    const int gNode  = (N + 31) / 32;             // 3125

    // ---- fused CSR bucket-sort + x@W1 (interleaved) ----
    k_init_cursor<<<1, 256, 0, stream>>>(cursor);
    k_fusedA<<<gBuild + gX64, 512, 0, stream>>>(row, col, cursor, bpack, x, W1, B0, E, N, gBuild);
    kC_fill <<<NB, 1024, 0, stream>>>(bpack, cursor, csr, rowptr, deg, dinv, B0, N);

    // ---- fused 3-layer GCN ----
    k_gxf2   <<<gNode, 256, 0, stream>>>(rowptr, deg, csr, B0, dinv, b1, W2, B1, N);
    k_gxf3   <<<gNode, 256, 0, stream>>>(rowptr, deg, csr, B1, dinv, b2, W3, s3, N);
    k_gather1<<<gNode, 256, 0, stream>>>(rowptr, deg, csr, s3, dinv, b3, out, N);
}

// Round 21
// 129.568 us; speedup vs baseline: 1.0549x; 1.0549x over previous
//
#include <hip/hip_runtime.h>
#include <hip/hip_fp16.h>

#define IN_DIM 128
#define HID    32
#define CHUNK  6144      // edges per sort block (12/thread)
#define EPT    12        // edges per thread in sort half
#define BSH    9         // log2(nodes per bucket)
#define BSIZE  512       // nodes per bucket
#define CAPSH  14        // per-bucket slot capacity = 16384 (mean 12245 + 37 sigma)
#define ROWBITS 17       // N = 100000 < 2^17
#define STRIDE 5         // sort blocks interleaved every STRIDE grid slots

typedef union { float2 f2; __half2 h2[2]; } hpack;

// cursor[b] = b * CAP
__global__ void k_init_cursor(int* __restrict__ cursor) {
    cursor[threadIdx.x] = threadIdx.x << CAPSH;
}

// ======================= fused: bucket-sort + x@W1, interleaved block mapping =======================

__global__ __launch_bounds__(512) void k_fusedA(const int* __restrict__ row,
                                                const int* __restrict__ col,
                                                int* __restrict__ cursor,
                                                int* __restrict__ bpack,
                                                const float* __restrict__ x,
                                                const float* __restrict__ W1,
                                                float* __restrict__ T0,
                                                int E, int N, int gBuild) {
    __shared__ __align__(16) char smem[34816];
    int tid = threadIdx.x;

    int b = blockIdx.x;
    int q = b / STRIDE, r = b % STRIDE;
    bool isSort = (r == 0) && (q < gBuild);

    if (isSort) {
        // ---- bucket counting sort (single edge read, rank from histogram atomic) ----
        int* lh   = (int*)smem;            // 256 counts (preserved)
        int* ls   = lh + 256;              // exclusive local starts
        int* gdst = ls + 256;              // global dst - local start
        int* sp   = gdst + 256;            // CHUNK packed edges
        unsigned char* sb = (unsigned char*)(sp + CHUNK); // CHUNK bucket ids

        if (tid < 256) lh[tid] = 0;
        __syncthreads();

        int base = q * CHUNK;
        int nE = min(CHUNK, E - base);
        int e0 = tid * EPT;
        int m  = min(EPT, nE - e0);

        int ecol[EPT], erow[EPT], rk[EPT];
        if (m == EPT) {
            int4 ca = *(const int4*)(col + base + e0);
            int4 cb = *(const int4*)(col + base + e0 + 4);
            int4 cc = *(const int4*)(col + base + e0 + 8);
            int4 ra = *(const int4*)(row + base + e0);
            int4 rb = *(const int4*)(row + base + e0 + 4);
            int4 rc = *(const int4*)(row + base + e0 + 8);
            ecol[0]=ca.x; ecol[1]=ca.y; ecol[2]=ca.z;  ecol[3]=ca.w;
            ecol[4]=cb.x; ecol[5]=cb.y; ecol[6]=cb.z;  ecol[7]=cb.w;
            ecol[8]=cc.x; ecol[9]=cc.y; ecol[10]=cc.z; ecol[11]=cc.w;
            erow[0]=ra.x; erow[1]=ra.y; erow[2]=ra.z;  erow[3]=ra.w;
            erow[4]=rb.x; erow[5]=rb.y; erow[6]=rb.z;  erow[7]=rb.w;
            erow[8]=rc.x; erow[9]=rc.y; erow[10]=rc.z; erow[11]=rc.w;
        } else {
            for (int j = 0; j < m; ++j) {
                ecol[j] = col[base + e0 + j];
                erow[j] = row[base + e0 + j];
            }
        }

        for (int j = 0; j < m; ++j)
            rk[j] = atomicAdd(&lh[ecol[j] >> BSH], 1);
        __syncthreads();

        int v = 0;
        if (tid < 256) { v = lh[tid]; ls[tid] = v; }
        __syncthreads();
        for (int off = 1; off < 256; off <<= 1) {
            int nv = 0;
            if (tid < 256) nv = ls[tid] + (tid >= off ? ls[tid - off] : 0);
            __syncthreads();
            if (tid < 256) ls[tid] = nv;
            __syncthreads();
        }
        if (tid < 256) ls[tid] -= v;
        __syncthreads();

        if (tid < 256) {
            int bb = (tid + q) & 255;
            int vb = lh[bb];
            if (vb) gdst[bb] = atomicAdd(&cursor[bb], vb) - ls[bb];
        }
        __syncthreads();

        for (int j = 0; j < m; ++j) {
            int c = ecol[j];
            int bk = c >> BSH;
            int idx = ls[bk] + rk[j];
            sp[idx] = ((c & (BSIZE - 1)) << ROWBITS) | erow[j];
            sb[idx] = (unsigned char)bk;
        }
        __syncthreads();

        for (int i = tid; i < nE; i += 512) {
            int bk = sb[i];
            bpack[gdst[bk] + i] = sp[i];
        }
    } else {
        // ---- t1 = x @ W1 (unscaled), fp16 out; float4 x loads, identical FMA order ----
        int xIdx = b - min(q + (r > 0 ? 1 : 0), gBuild);   // compact xform index

        float* lw = (float*)smem;          // 16 KB
        for (int i = tid; i < IN_DIM * HID; i += 512) lw[i] = W1[i];
        __syncthreads();

        int lane = tid & 7;
        int jb = lane * 4;
        int n  = xIdx * 64 + (tid >> 3);
        if (n >= N) return;

        const float4* xr4 = (const float4*)(x + (size_t)n * IN_DIM);
        float a0 = 0.f, a1 = 0.f, a2 = 0.f, a3 = 0.f;
        #pragma unroll 8
        for (int kq = 0; kq < IN_DIM / 4; ++kq) {
            float4 v = xr4[kq];
            const float* w0 = &lw[(kq * 4 + 0) * HID + jb];
            const float* w1 = &lw[(kq * 4 + 1) * HID + jb];
            const float* w2 = &lw[(kq * 4 + 2) * HID + jb];
            const float* w3 = &lw[(kq * 4 + 3) * HID + jb];
            a0 = fmaf(v.x, w0[0], a0); a1 = fmaf(v.x, w0[1], a1);
            a2 = fmaf(v.x, w0[2], a2); a3 = fmaf(v.x, w0[3], a3);
            a0 = fmaf(v.y, w1[0], a0); a1 = fmaf(v.y, w1[1], a1);
            a2 = fmaf(v.y, w1[2], a2); a3 = fmaf(v.y, w1[3], a3);
            a0 = fmaf(v.z, w2[0], a0); a1 = fmaf(v.z, w2[1], a1);
            a2 = fmaf(v.z, w2[2], a2); a3 = fmaf(v.z, w2[3], a3);
            a0 = fmaf(v.w, w3[0], a0); a1 = fmaf(v.w, w3[1], a1);
            a2 = fmaf(v.w, w3[2], a2); a3 = fmaf(v.w, w3[3], a3);
        }
        hpack u;
        u.h2[0] = __floats2half2_rn(a0, a1);
        u.h2[1] = __floats2half2_rn(a2, a3);
        ((float2*)T0)[(size_t)n * 8 + lane] = u.f2;
    }
}

// ======================= kC: per-bucket CSR fill + deg/dinv + B0 scale =======================

__global__ __launch_bounds__(1024) void kC_fill(const int* __restrict__ bpack,
                                                const int* __restrict__ cursor,
                                                int* __restrict__ csr,
                                                int* __restrict__ rowptr,
                                                int* __restrict__ deg,
                                                float* __restrict__ dinv,
                                                float* __restrict__ B0, int N) {
    __shared__ int cnt[BSIZE], ex[BSIZE], c2[BSIZE];
    __shared__ int sp[1 << CAPSH];     // 64 KB staged bucket edges
    int tid = threadIdx.x;
    int b = blockIdx.x;
    int s = b << CAPSH;
    int ne = cursor[b] - s;
    int c0 = b << BSH;

    if (tid < BSIZE) { cnt[tid] = 0; c2[tid] = 0; }
    __syncthreads();

    // 1) stage + degree histogram
    for (int i = tid; i < ne; i += 1024) {
        int v = bpack[s + i];
        sp[i] = v;
        atomicAdd(&cnt[v >> ROWBITS], 1);
    }
    __syncthreads();

    // 2) inclusive scan of 512 counts
    if (tid < BSIZE) ex[tid] = cnt[tid];
    __syncthreads();
    for (int off = 1; off < BSIZE; off <<= 1) {
        int nv = 0;
        if (tid < BSIZE) nv = ex[tid] + (tid >= off ? ex[tid - off] : 0);
        __syncthreads();
        if (tid < BSIZE) ex[tid] = nv;
        __syncthreads();
    }

    // 3) to exclusive; emit rowptr / deg / dinv
    if (tid < BSIZE) {
        int ev = ex[tid] - cnt[tid];
        ex[tid] = ev;
        int n = c0 + tid;
        if (n < N) {
            rowptr[n] = s + ev;
            deg[n]    = cnt[tid];
            dinv[n]   = rsqrtf((float)cnt[tid] + 1.0f);
        }
    }
    __syncthreads();

    // 4) fill csr from LDS
    for (int i = tid; i < ne; i += 1024) {
        int v = sp[i];
        int c = v >> ROWBITS;
        int k = atomicAdd(&c2[c], 1);
        csr[s + ex[c] + k] = v & ((1 << ROWBITS) - 1);
    }

    // 5) scale T0 rows by dinv -> B0 in place (row = 4 float4s)
    for (int j = tid; j < BSIZE * 4; j += 1024) {
        int nl = j >> 2;
        int n = c0 + nl;
        if (n < N) {
            float dv = rsqrtf((float)cnt[nl] + 1.0f);
            union { float4 f4; __half2 h2[4]; } u;
            u.f4 = ((const float4*)B0)[(size_t)n * 4 + (j & 3)];
            #pragma unroll
            for (int qq = 0; qq < 4; ++qq) {
                float2 f = __half22float2(u.h2[qq]);
                u.h2[qq] = __floats2half2_rn(f.x * dv, f.y * dv);
            }
            ((float4*)B0)[(size_t)n * 4 + (j & 3)] = u.f4;
        }
    }
}

// ======================= fused gather + transform kernels (sequential node order) =======================

#define GLOAD(i, r) hpack p##i; p##i.f2 = B2[(size_t)(r) * 8 + lane]
#define GACC(i) { float2 a = __half22float2(p##i.h2[0]), b = __half22float2(p##i.h2[1]); \
                  acc.x += a.x; acc.y += a.y; acc.z += b.x; acc.w += b.y; }

// gather(B0) -> h1 = relu(...) -> s2 = dinv * (h1 @ W2), fp16 out. H never stored.
__global__ __launch_bounds__(256) void k_gxf2(const int* __restrict__ rowptr,
                                              const int* __restrict__ deg,
                                              const int* __restrict__ csr,
                                              const float* __restrict__ Bin,
                                              const float* __restrict__ dinv,
                                              const float* __restrict__ bias,
                                              const float* __restrict__ W2,
                                              float* __restrict__ Bout, int N) {
    __shared__ float lw[HID * HID];
    for (int i = threadIdx.x; i < HID * HID; i += 256) lw[i] = W2[i];
    __syncthreads();

    int lane = threadIdx.x & 7;
    int jb = lane * 4;
    int n  = blockIdx.x * 32 + (threadIdx.x >> 3);
    if (n >= N) return;

    const float2* B2 = (const float2*)Bin;
    hpack u0; u0.f2 = B2[(size_t)n * 8 + lane];     // self-loop term
    float2 l0 = __half22float2(u0.h2[0]);
    float2 l1 = __half22float2(u0.h2[1]);
    float4 acc = make_float4(l0.x, l0.y, l1.x, l1.y);

    int s = rowptr[n], cnt = deg[n];
    int k = 0;
    for (; k + 7 < cnt; k += 8) {
        int r0 = csr[s+k],   r1 = csr[s+k+1], r2 = csr[s+k+2], r3 = csr[s+k+3];
        int r4 = csr[s+k+4], r5 = csr[s+k+5], r6 = csr[s+k+6], r7 = csr[s+k+7];
        GLOAD(0, r0); GLOAD(1, r1); GLOAD(2, r2); GLOAD(3, r3);
        GLOAD(4, r4); GLOAD(5, r5); GLOAD(6, r6); GLOAD(7, r7);
        GACC(0); GACC(1); GACC(2); GACC(3); GACC(4); GACC(5); GACC(6); GACC(7);
    }
    for (; k + 3 < cnt; k += 4) {
        int r0 = csr[s+k], r1 = csr[s+k+1], r2 = csr[s+k+2], r3 = csr[s+k+3];
        GLOAD(0, r0); GLOAD(1, r1); GLOAD(2, r2); GLOAD(3, r3);
        GACC(0); GACC(1); GACC(2); GACC(3);
    }
    for (; k < cnt; ++k) {
        GLOAD(0, csr[s+k]); GACC(0);
    }
    float dv = dinv[n];
    float4 b4 = ((const float4*)bias)[lane];
    float4 o;
    o.x = fmaxf(fmaf(dv, acc.x, b4.x), 0.f);
    o.y = fmaxf(fmaf(dv, acc.y, b4.y), 0.f);
    o.z = fmaxf(fmaf(dv, acc.z, b4.z), 0.f);
    o.w = fmaxf(fmaf(dv, acc.w, b4.w), 0.f);

    // fused h1 @ W2 across the 8-lane group
    float t0 = 0.f, t1 = 0.f, t2 = 0.f, t3 = 0.f;
    #pragma unroll
    for (int sl = 0; sl < 8; ++sl) {
        float h0 = __shfl(o.x, sl, 8);
        float h1 = __shfl(o.y, sl, 8);
        float h2 = __shfl(o.z, sl, 8);
        float h3 = __shfl(o.w, sl, 8);
        const float* w0 = &lw[(sl * 4 + 0) * HID + jb];
        const float* w1 = &lw[(sl * 4 + 1) * HID + jb];
        const float* w2 = &lw[(sl * 4 + 2) * HID + jb];
        const float* w3 = &lw[(sl * 4 + 3) * HID + jb];
        t0 = fmaf(h0, w0[0], t0); t1 = fmaf(h0, w0[1], t1);
        t2 = fmaf(h0, w0[2], t2); t3 = fmaf(h0, w0[3], t3);
        t0 = fmaf(h1, w1[0], t0); t1 = fmaf(h1, w1[1], t1);
        t2 = fmaf(h1, w1[2], t2); t3 = fmaf(h1, w1[3], t3);
        t0 = fmaf(h2, w2[0], t0); t1 = fmaf(h2, w2[1], t1);
        t2 = fmaf(h2, w2[2], t2); t3 = fmaf(h2, w2[3], t3);
        t0 = fmaf(h3, w3[0], t0); t1 = fmaf(h3, w3[1], t1);
        t2 = fmaf(h3, w3[2], t2); t3 = fmaf(h3, w3[3], t3);
    }
    hpack w;
    w.h2[0] = __floats2half2_rn(t0 * dv, t1 * dv);
    w.h2[1] = __floats2half2_rn(t2 * dv, t3 * dv);
    ((float2*)Bout)[(size_t)n * 8 + lane] = w.f2;
}

// gather(B1) -> h2 = relu(...) -> s3 = dinv * (h2 . W3), f32 scalar out.
__global__ __launch_bounds__(256) void k_gxf3(const int* __restrict__ rowptr,
                                              const int* __restrict__ deg,
                                              const int* __restrict__ csr,
                                              const float* __restrict__ Bin,
                                              const float* __restrict__ dinv,
                                              const float* __restrict__ bias,
                                              const float* __restrict__ W3,
                                              float* __restrict__ s3, int N) {
    __shared__ float lw[HID];
    if (threadIdx.x < HID) lw[threadIdx.x] = W3[threadIdx.x];
    __syncthreads();

    int lane = threadIdx.x & 7;
    int jb = lane * 4;
    int n  = blockIdx.x * 32 + (threadIdx.x >> 3);
    if (n >= N) return;

    const float2* B2 = (const float2*)Bin;
    hpack u0; u0.f2 = B2[(size_t)n * 8 + lane];
    float2 l0 = __half22float2(u0.h2[0]);
    float2 l1 = __half22float2(u0.h2[1]);
    float4 acc = make_float4(l0.x, l0.y, l1.x, l1.y);

    int s = rowptr[n], cnt = deg[n];
    int k = 0;
    for (; k + 7 < cnt; k += 8) {
        int r0 = csr[s+k],   r1 = csr[s+k+1], r2 = csr[s+k+2], r3 = csr[s+k+3];
        int r4 = csr[s+k+4], r5 = csr[s+k+5], r6 = csr[s+k+6], r7 = csr[s+k+7];
        GLOAD(0, r0); GLOAD(1, r1); GLOAD(2, r2); GLOAD(3, r3);
        GLOAD(4, r4); GLOAD(5, r5); GLOAD(6, r6); GLOAD(7, r7);
        GACC(0); GACC(1); GACC(2); GACC(3); GACC(4); GACC(5); GACC(6); GACC(7);
    }
    for (; k + 3 < cnt; k += 4) {
        int r0 = csr[s+k], r1 = csr[s+k+1], r2 = csr[s+k+2], r3 = csr[s+k+3];
        GLOAD(0, r0); GLOAD(1, r1); GLOAD(2, r2); GLOAD(3, r3);
        GACC(0); GACC(1); GACC(2); GACC(3);
    }
    for (; k < cnt; ++k) {
        GLOAD(0, csr[s+k]); GACC(0);
    }
    float dv = dinv[n];
    float4 b4 = ((const float4*)bias)[lane];
    float4 o;
    o.x = fmaxf(fmaf(dv, acc.x, b4.x), 0.f);
    o.y = fmaxf(fmaf(dv, acc.y, b4.y), 0.f);
    o.z = fmaxf(fmaf(dv, acc.z, b4.z), 0.f);
    o.w = fmaxf(fmaf(dv, acc.w, b4.w), 0.f);

    float p = o.x * lw[jb] + o.y * lw[jb + 1] + o.z * lw[jb + 2] + o.w * lw[jb + 3];
    p += __shfl_xor(p, 1, 8);
    p += __shfl_xor(p, 2, 8);
    p += __shfl_xor(p, 4, 8);
    if (lane == 0) s3[n] = p * dv;
}

// out[n] = dinv[n] * (s3[n] + sum_nbrs s3[r]) + b3 ; 8 lanes/node strided.
__global__ __launch_bounds__(256) void k_gather1(const int* __restrict__ rowptr,
                                                 const int* __restrict__ deg,
                                                 const int* __restrict__ csr,
                                                 const float* __restrict__ s3,
                                                 const float* __restrict__ dinv,
                                                 const float* __restrict__ b3,
                                                 float* __restrict__ out, int N) {
    int lane = threadIdx.x & 7;
    int n    = blockIdx.x * 32 + (threadIdx.x >> 3);
    if (n >= N) return;

    int s = rowptr[n], cnt = deg[n];
    float acc = 0.f;
    for (int k = lane; k < cnt; k += 8) acc += s3[csr[s + k]];
    acc += __shfl_xor(acc, 1, 8);
    acc += __shfl_xor(acc, 2, 8);
    acc += __shfl_xor(acc, 4, 8);
    if (lane == 0) out[n] = fmaf(dinv[n], acc + s3[n], b3[0]);
}

// ======================= host launch =======================

static inline size_t align64(size_t x) { return (x + 63) & ~(size_t)63; }

extern "C" void kernel_launch(void* const* d_in, const int* in_sizes, int n_in,
                              void* d_out, int out_size, void* d_ws, size_t ws_size,
                              hipStream_t stream) {
    const float* x   = (const float*)d_in[0];
    const int*   ei  = (const int*)d_in[1];   // jax x64 disabled -> int32
    const float* W1  = (const float*)d_in[2];
    const float* b1  = (const float*)d_in[3];
    const float* W2  = (const float*)d_in[4];
    const float* b2  = (const float*)d_in[5];
    const float* W3  = (const float*)d_in[6];
    const float* b3  = (const float*)d_in[7];

    const int N = in_sizes[0] / IN_DIM;       // 100000
    const int E = in_sizes[1] / 2;            // 2400000
    const int* row = ei;                       // message source
    const int* col = ei + E;                   // aggregation target

    const int NB = (N + BSIZE - 1) / BSIZE;    // 196 buckets
    const size_t bktCap = (size_t)NB << CAPSH; // padded slot count

    // workspace layout (64B-aligned regions)
    char* p = (char*)d_ws;
    size_t off = 0;
    float* dinv   = (float*)(p + off); off = align64(off + (size_t)N * 4);
    float* B0     = (float*)(p + off); off = align64(off + (size_t)N * HID * 2);  // fp16 msgs
    float* B1     = (float*)(p + off); off = align64(off + (size_t)N * HID * 2);  // fp16 msgs
    float* s3     = (float*)(p + off); off = align64(off + (size_t)N * 4);
    int*   deg    = (int*)  (p + off); off = align64(off + (size_t)N * 4);
    int*   rowptr = (int*)  (p + off); off = align64(off + (size_t)N * 4);
    int*   cursor = (int*)  (p + off); off = align64(off + 256 * 4);
    int*   bpack  = (int*)  (p + off); off = align64(off + bktCap * 4);
    int*   csr    = (int*)  (p + off); off = align64(off + bktCap * 4);
    float* out    = (float*)d_out;

    const int gBuild = (E + CHUNK - 1) / CHUNK;   // 391
    const int gX64   = (N + 63) / 64;             // 1563 (xform part, 64 nodes/block)
    const int gNode  = (N + 31) / 32;             // 3125

    // ---- fused CSR bucket-sort + x@W1 (interleaved) ----
    k_init_cursor<<<1, 256, 0, stream>>>(cursor);
    k_fusedA<<<gBuild + gX64, 512, 0, stream>>>(row, col, cursor, bpack, x, W1, B0, E, N, gBuild);
    kC_fill <<<NB, 1024, 0, stream>>>(bpack, cursor, csr, rowptr, deg, dinv, B0, N);

    // ---- fused 3-layer GCN ----
    k_gxf2   <<<gNode, 256, 0, stream>>>(rowptr, deg, csr, B0, dinv, b1, W2, B1, N);
    k_gxf3   <<<gNode, 256, 0, stream>>>(rowptr, deg, csr, B1, dinv, b2, W3, s3, N);
    k_gather1<<<gNode, 256, 0, stream>>>(rowptr, deg, csr, s3, dinv, b3, out, N);
}